// Round 1
// baseline (170.003 us; speedup 1.0000x reference)
//
#include <hip/hip_runtime.h>
#include <math.h>

#define D_MODEL 1024
#define N_HEADS 8
#define HEAD_DIM 128
#define T_TOKENS 8193

// ---- workspace layout (float offsets) ----
#define OFF_QCLS   0        // 1024
#define OFF_W      1024     // 8*1024 = 8192
#define OFF_SCORES 9216     // 8*8193 = 65544
#define OFF_M      74760    // 8
#define OFF_L      74768    // 8
#define OFF_U      74776    // 8192
#define OFF_ATT    82968    // 1024
#define OFF_CLS    83992    // 1024
#define OFF_PART   85024    // TC*4*2048 floats

static __device__ __forceinline__ float block_reduce_sum_256(float v, float* red) {
    int t = threadIdx.x;
    #pragma unroll
    for (int off = 32; off > 0; off >>= 1) v += __shfl_down(v, off, 64);
    __syncthreads();               // protect red from previous use
    if ((t & 63) == 0) red[t >> 6] = v;
    __syncthreads();
    return red[0] + red[1] + red[2] + red[3];
}

// K1: q_cls[r] = Wq[r,:] . cls_token + bq[r]   (grid 1024, block 256)
__global__ __launch_bounds__(256) void k_qcls(const float* __restrict__ Wq,
                                              const float* __restrict__ bq,
                                              const float* __restrict__ ct,
                                              float* __restrict__ ws) {
    __shared__ float red[4];
    int r = blockIdx.x, t = threadIdx.x;
    const float4* wr = (const float4*)(Wq + (size_t)r * D_MODEL);
    const float4* cv = (const float4*)ct;
    float4 a = wr[t], b = cv[t];
    float v = a.x*b.x + a.y*b.y + a.z*b.z + a.w*b.w;
    v = block_reduce_sum_256(v, red);
    if (t == 0) ws[OFF_QCLS + r] = v + bq[r];
}

// K2: w[h][j] = sum_d qcls[h*128+d] * Wk[h*128+d][j]   (grid 32, block 256)
__global__ __launch_bounds__(256) void k_wvec(const float* __restrict__ Wk,
                                              float* __restrict__ ws) {
    __shared__ float qh[HEAD_DIM];
    int t = threadIdx.x;
    int h = blockIdx.x >> 2;                 // 4 blocks per head
    int j = (blockIdx.x * 256 + t) & (D_MODEL - 1);
    if (t < HEAD_DIM) qh[t] = ws[OFF_QCLS + h * HEAD_DIM + t];
    __syncthreads();
    float acc = 0.f;
    const float* wp = Wk + (size_t)(h * HEAD_DIM) * D_MODEL + j;
    #pragma unroll 4
    for (int d = 0; d < HEAD_DIM; ++d) acc += qh[d] * wp[(size_t)d * D_MODEL];
    ws[OFF_W + h * D_MODEL + j] = acc;
}

// K3: scores[h][s] = scale*(w[h].tok[s] + c[h])   wave-per-token (grid 2049, block 256)
__global__ __launch_bounds__(256) void k_scores(const float* __restrict__ x,
                                                const float* __restrict__ ct,
                                                const float* __restrict__ bk,
                                                float* __restrict__ ws) {
    __shared__ float wlds[N_HEADS * D_MODEL];   // 32 KiB
    __shared__ float clds[N_HEADS];
    int t = threadIdx.x;
    float4* wl4 = (float4*)wlds;
    const float4* wg4 = (const float4*)(ws + OFF_W);
    #pragma unroll
    for (int i = 0; i < 8; ++i) wl4[t + 256 * i] = wg4[t + 256 * i];
    if (t < N_HEADS) {
        float c = 0.f;
        const float* q = ws + OFF_QCLS + t * HEAD_DIM;
        const float* b = bk + t * HEAD_DIM;
        #pragma unroll 8
        for (int d = 0; d < HEAD_DIM; ++d) c += q[d] * b[d];
        clds[t] = c;
    }
    __syncthreads();
    int wid = t >> 6, lane = t & 63;
    int s = blockIdx.x * 4 + wid;
    if (s >= T_TOKENS) return;
    const float4* tok = (const float4*)((s == 0) ? ct : (x + (size_t)(s - 1) * D_MODEL));
    float acc[8];
    #pragma unroll
    for (int h = 0; h < 8; ++h) acc[h] = 0.f;
    #pragma unroll
    for (int i = 0; i < 4; ++i) {
        int f4 = lane + 64 * i;
        float4 tv = tok[f4];
        #pragma unroll
        for (int h = 0; h < 8; ++h) {
            float4 wv = ((const float4*)(wlds + h * D_MODEL))[f4];
            acc[h] += wv.x*tv.x + wv.y*tv.y + wv.z*tv.z + wv.w*tv.w;
        }
    }
    #pragma unroll
    for (int h = 0; h < 8; ++h) {
        float v = acc[h];
        #pragma unroll
        for (int off = 32; off > 0; off >>= 1) v += __shfl_down(v, off, 64);
        acc[h] = v;
    }
    if (lane == 0) {
        const float scale = 0.08838834764831845f;   // 1/sqrt(128)
        #pragma unroll
        for (int h = 0; h < 8; ++h)
            ws[OFF_SCORES + h * T_TOKENS + s] = scale * (acc[h] + clds[h]);
    }
}

// K4: per-head max & sum-exp over T; also zero u accumulator. (grid 8, block 256)
__global__ __launch_bounds__(256) void k_stats(float* __restrict__ ws) {
    __shared__ float red[4];
    __shared__ float msh;
    int h = blockIdx.x, t = threadIdx.x;
    // zero u slice (consumed by K6 atomics)
    for (int i = t; i < D_MODEL; i += 256) ws[OFF_U + h * D_MODEL + i] = 0.f;
    const float* sc = ws + OFF_SCORES + h * T_TOKENS;
    float mx = -1e30f;
    for (int i = t; i < T_TOKENS; i += 256) mx = fmaxf(mx, sc[i]);
    #pragma unroll
    for (int off = 32; off > 0; off >>= 1) mx = fmaxf(mx, __shfl_down(mx, off, 64));
    __syncthreads();
    if ((t & 63) == 0) red[t >> 6] = mx;
    __syncthreads();
    if (t == 0) msh = fmaxf(fmaxf(red[0], red[1]), fmaxf(red[2], red[3]));
    __syncthreads();
    float m = msh;
    float sm = 0.f;
    for (int i = t; i < T_TOKENS; i += 256) sm += expf(sc[i] - m);
    sm = block_reduce_sum_256(sm, red);
    if (t == 0) { ws[OFF_M + h] = m; ws[OFF_L + h] = sm; }
}

// K5: probs -> A output; partial u[h][j] per (jc, tc) block.
// grid (4, TC), block 256. Thread: wave hp owns heads (2hp,2hp+1); lane -> float4 j-slice.
__global__ __launch_bounds__(256) void k_probs_u(const float* __restrict__ x,
                                                 const float* __restrict__ ct,
                                                 float* __restrict__ out,
                                                 float* __restrict__ ws,
                                                 int chunkT) {
    __shared__ float plds[N_HEADS][32];
    int jc = blockIdx.x;           // 0..3  (256 floats of the row each)
    int tc = blockIdx.y;
    int t = threadIdx.x;
    int hp = t >> 6, lane = t & 63;
    int h0 = hp * 2, h1 = h0 + 1;
    int j4 = jc * 64 + lane;       // float4 index in [0,256)
    int start = tc * chunkT;
    int end = min(start + chunkT, T_TOKENS);
    float m[8], rl[8];
    #pragma unroll
    for (int h = 0; h < 8; ++h) { m[h] = ws[OFF_M + h]; rl[h] = 1.f / ws[OFF_L + h]; }
    float4 acc0 = {0,0,0,0}, acc1 = {0,0,0,0};
    int hh = t >> 5, si = t & 31;
    for (int s0 = start; s0 < end; s0 += 32) {
        int nt = min(32, end - s0);
        float p = 0.f;
        if (si < nt) p = expf(ws[OFF_SCORES + hh * T_TOKENS + s0 + si] - m[hh]) * rl[hh];
        __syncthreads();           // finish previous iter's plds reads
        plds[hh][si] = p;
        __syncthreads();
        if (jc == 0 && t < nt && (s0 + t) >= 1) {
            float sum = 0.f;
            #pragma unroll
            for (int h = 0; h < 8; ++h) sum += plds[h][t];
            out[7 + (s0 + t) - 1] = sum * 0.125f;
        }
        #pragma unroll 4
        for (int k = 0; k < nt; ++k) {
            int s = s0 + k;
            const float4* tok = (const float4*)((s == 0) ? ct : (x + (size_t)(s - 1) * D_MODEL));
            float4 tv = tok[j4];
            float p0 = plds[h0][k], p1 = plds[h1][k];
            acc0.x += p0 * tv.x; acc0.y += p0 * tv.y; acc0.z += p0 * tv.z; acc0.w += p0 * tv.w;
            acc1.x += p1 * tv.x; acc1.y += p1 * tv.y; acc1.z += p1 * tv.z; acc1.w += p1 * tv.w;
        }
    }
    float* base = ws + OFF_PART + (size_t)(tc * 4 + jc) * 2048;
    ((float4*)(base + h0 * 256))[lane] = acc0;
    ((float4*)(base + h1 * 256))[lane] = acc1;
}

// K6: u[h*1024+j] += sum over token-chunks of partials.  grid (32, 4), block 256.
__global__ __launch_bounds__(256) void k_ureduce(float* __restrict__ ws, int TC, int seg) {
    int j = blockIdx.x * 256 + threadIdx.x;      // 0..8191
    int h = j >> 10, jj = j & 1023;
    int jc = jj >> 8, jr = jj & 255;
    int t0 = blockIdx.y * seg;
    int t1 = min(t0 + seg, TC);
    float acc = 0.f;
    for (int tcb = t0; tcb < t1; ++tcb)
        acc += ws[OFF_PART + (size_t)(tcb * 4 + jc) * 2048 + h * 256 + jr];
    atomicAdd(&ws[OFF_U + j], acc);
}

// K7: attn_out[r] = Wv[r,:] . u[head(r),:] + bv[r]   (grid 1024, block 256)
__global__ __launch_bounds__(256) void k_attnout(const float* __restrict__ Wv,
                                                 const float* __restrict__ bv,
                                                 float* __restrict__ ws) {
    __shared__ float red[4];
    int r = blockIdx.x, t = threadIdx.x;
    int h = r >> 7;
    const float4* wr = (const float4*)(Wv + (size_t)r * D_MODEL);
    const float4* uu = (const float4*)(ws + OFF_U + h * D_MODEL);
    float4 a = wr[t], b = uu[t];
    float v = a.x*b.x + a.y*b.y + a.z*b.z + a.w*b.w;
    v = block_reduce_sum_256(v, red);
    if (t == 0) ws[OFF_ATT + r] = v + bv[r];
}

// K8: cls_out[r] = Wo[r,:] . attn_out + bo[r]   (grid 1024, block 256)
__global__ __launch_bounds__(256) void k_clsout(const float* __restrict__ Wo,
                                                const float* __restrict__ bo,
                                                float* __restrict__ ws) {
    __shared__ float red[4];
    int r = blockIdx.x, t = threadIdx.x;
    const float4* wr = (const float4*)(Wo + (size_t)r * D_MODEL);
    const float4* av = (const float4*)(ws + OFF_ATT);
    float4 a = wr[t], b = av[t];
    float v = a.x*b.x + a.y*b.y + a.z*b.z + a.w*b.w;
    v = block_reduce_sum_256(v, red);
    if (t == 0) ws[OFF_CLS + r] = v + bo[r];
}

// K9: logits, softmax, argmax, scalar outputs. (grid 1, block 256)
__global__ __launch_bounds__(256) void k_final(const float* __restrict__ Wc,
                                               const float* __restrict__ bc,
                                               float* __restrict__ out,
                                               float* __restrict__ ws) {
    __shared__ float red[4];
    int t = threadIdx.x;
    const float* cls = ws + OFF_CLS;
    float a0 = 0.f, a1 = 0.f;
    for (int j = t; j < D_MODEL; j += 256) {
        float c = cls[j];
        a0 += Wc[j] * c;
        a1 += Wc[D_MODEL + j] * c;
    }
    a0 = block_reduce_sum_256(a0, red);
    a1 = block_reduce_sum_256(a1, red);
    if (t == 0) {
        float l0 = a0 + bc[0], l1 = a1 + bc[1];
        float mx = fmaxf(l0, l1);
        float e0 = expf(l0 - mx), e1 = expf(l1 - mx);
        float inv = 1.f / (e0 + e1);
        float p0 = e0 * inv, p1 = e1 * inv;
        int am = (p1 > p0) ? 1 : 0;      // first-max tie rule like jnp.argmax
        out[0] = l0; out[1] = l1;        // top_instance
        out[2] = p0; out[3] = p1;        // Y_prob
        out[4] = (float)am;              // Y_hat
        out[5] = p0; out[6] = p1;        // y_probs
    }
}

extern "C" void kernel_launch(void* const* d_in, const int* in_sizes, int n_in,
                              void* d_out, int out_size, void* d_ws, size_t ws_size,
                              hipStream_t stream) {
    const float* x  = (const float*)d_in[0];
    const float* ct = (const float*)d_in[1];
    const float* Wq = (const float*)d_in[2];
    const float* bq = (const float*)d_in[3];
    const float* Wk = (const float*)d_in[4];
    const float* bk = (const float*)d_in[5];
    const float* Wv = (const float*)d_in[6];
    const float* bv = (const float*)d_in[7];
    const float* Wo = (const float*)d_in[8];
    const float* bo = (const float*)d_in[9];
    const float* Wc = (const float*)d_in[10];
    const float* bc = (const float*)d_in[11];
    float* out = (float*)d_out;
    float* ws  = (float*)d_ws;

    // adaptive partial-buffer sizing: TC token-chunks, each (4 jc) blocks of 2048 floats
    long availf = (long)(ws_size / 4) - OFF_PART;
    int TC = (int)(availf / (4 * 2048));
    if (TC > 129) TC = 129;
    if (TC < 1) TC = 1;
    int chunkT = (T_TOKENS + TC - 1) / TC;
    int seg = (TC + 3) / 4;

    k_qcls   <<<dim3(1024),        dim3(256), 0, stream>>>(Wq, bq, ct, ws);
    k_wvec   <<<dim3(32),          dim3(256), 0, stream>>>(Wk, ws);
    k_scores <<<dim3(2049),        dim3(256), 0, stream>>>(x, ct, bk, ws);
    k_stats  <<<dim3(8),           dim3(256), 0, stream>>>(ws);
    k_probs_u<<<dim3(4, TC),       dim3(256), 0, stream>>>(x, ct, out, ws, chunkT);
    k_ureduce<<<dim3(32, 4),       dim3(256), 0, stream>>>(ws, TC, seg);
    k_attnout<<<dim3(1024),        dim3(256), 0, stream>>>(Wv, bv, ws);
    k_clsout <<<dim3(1024),        dim3(256), 0, stream>>>(Wo, bo, ws);
    k_final  <<<dim3(1),           dim3(256), 0, stream>>>(Wc, bc, out, ws);
}